// Round 1
// 509.613 us; speedup vs baseline: 1.0860x; 1.0860x over previous
//
#include <hip/hip_runtime.h>
#include <cmath>

#define NB 32
#define NH 8
#define NL 2048
#define NE 64

// One block = 64 consecutive l-rows of one (b,h). 256 threads = 4 waves.
// Phase B mapping: wave w -> d-range [16w, 16w+16), lane -> row.
//
// LDS layout: qb/kk are [64 rows][16 granules x 4 floats], row stride 256B
// (multiple of the 128B bank row). Phase A/B use granule-index XOR (row&7)
// so that 8 consecutive lanes (which read the same logical granule of their
// own row) cover all 32 banks -> conflict-free ds_read_b128.
// Phase C/D re-stage v into qb with a granule ROTATION by (row&7), which
// folds into the delay offset for free in the scalar gather.
__global__ __launch_bounds__(256, 4) void autocorr_kernel(
    const float* __restrict__ qg_,
    const float* __restrict__ kg_,
    const float* __restrict__ vg_,
    float* __restrict__ outV,   // (B,H,L,E)
    float* __restrict__ outC)   // (B,E,H,L)
{
    __shared__ alignas(16) float qb[64][64];       // q (XOR-swizzled); later v (rotated)
    __shared__ alignas(16) float kk[64][64];       // k (XOR-swizzled), wrap via granule index
    __shared__ float        cval[64][17];          // per-thread top-4 values (stride 17: odd mod 32)
    __shared__ unsigned int cidx4[64][5];          // packed 4x u8 indices per wave (stride 5)
    __shared__ float        wts[64][5];            // softmaxed weights (stride 5)
    __shared__ unsigned int dpack[64];             // packed 4x u8 delays

    const int tid  = threadIdx.x;
    const int tile = blockIdx.x & 31;   // L/64 = 32 tiles
    const int bh   = blockIdx.x >> 5;   // b*H + h
    const int b    = bh >> 3;
    const int h    = bh & 7;
    const int l0   = tile * 64;
    const size_t rowbase = (size_t)bh * NL + l0;

    const float4* q4 = (const float4*)(qg_ + rowbase * NE);
    const float4* k4 = (const float4*)(kg_ + rowbase * NE);
    const float4* v4 = (const float4*)(vg_ + rowbase * NE);

    // ---- Phase A: stage q, k (coalesced float4), granule-XOR swizzle ----
    #pragma unroll
    for (int i = 0; i < 4; i++) {
        int idx = tid + i * 256;          // 0..1023 float4 = 64 rows x 16 granules
        int r = idx >> 4, g = idx & 15;
        int gs = (g ^ (r & 7)) * 4;
        float4 qv = q4[idx];
        float4 kv = k4[idx];
        *(float4*)&qb[r][gs] = qv;
        *(float4*)&kk[r][gs] = kv;
    }
    __syncthreads();

    // ---- Phase B: corr[d] = sum_t q[t] * k[(t-d) & 63] ----
    const int wv = tid >> 6;   // wave id
    const int r  = tid & 63;   // row (lane)
    const int d0 = wv * 16;
    const int rq = r & 7;

    float acc[16];
    #pragma unroll
    for (int u = 0; u < 16; u++) acc[u] = 0.f;

    const float* qrow = &qb[r][0];
    const float* krow = &kk[r][0];

    #pragma unroll
    for (int c = 0; c < 64; c += 16) {
        float qv[16];
        #pragma unroll
        for (int i = 0; i < 4; i++) {
            float4 t = *(const float4*)(qrow + (((c >> 2) + i) ^ rq) * 4);
            qv[i*4+0]=t.x; qv[i*4+1]=t.y; qv[i*4+2]=t.z; qv[i*4+3]=t.w;
        }
        float kv[32];
        const int gs0 = (64 + c - d0 - 16) >> 2;   // multiple of 4, in [0,24]
        #pragma unroll
        for (int i = 0; i < 8; i++) {
            float4 t = *(const float4*)(krow + ((((gs0 + i) & 15) ^ rq) * 4));
            kv[i*4+0]=t.x; kv[i*4+1]=t.y; kv[i*4+2]=t.z; kv[i*4+3]=t.w;
        }
        // kv[m] = k[(c - d0 - 16 + m) & 63]; need k[(c+tt) - (d0+u)] -> m = tt - u + 16 in [1,31]
        #pragma unroll
        for (int u = 0; u < 16; u++) {
            #pragma unroll
            for (int tt = 0; tt < 16; tt++) {
                acc[u] = fmaf(qv[tt], kv[tt - u + 16], acc[u]);
            }
        }
    }

    // corr -> transposed output (B,E,H,L); lane = l -> coalesced
    {
        float* oc = outC + ((size_t)(b * NE + d0) * NH + h) * NL + l0 + r;
        #pragma unroll
        for (int u = 0; u < 16; u++) {
            oc[(size_t)u * (NH * NL)] = acc[u];
        }
    }

    // per-thread top-4 of this thread's 16 corr values
    float bv[4] = {-3.0e38f, -3.0e38f, -3.0e38f, -3.0e38f};
    int   bi[4] = {0, 0, 0, 0};
    #pragma unroll
    for (int u = 0; u < 16; u++) {
        float x = acc[u]; int ix = d0 + u;
        if (x > bv[3]) {
            if (x > bv[1]) {
                if (x > bv[0]) { bv[3]=bv[2];bi[3]=bi[2]; bv[2]=bv[1];bi[2]=bi[1]; bv[1]=bv[0];bi[1]=bi[0]; bv[0]=x; bi[0]=ix; }
                else           { bv[3]=bv[2];bi[3]=bi[2]; bv[2]=bv[1];bi[2]=bi[1]; bv[1]=x; bi[1]=ix; }
            } else {
                if (x > bv[2]) { bv[3]=bv[2];bi[3]=bi[2]; bv[2]=x; bi[2]=ix; }
                else           { bv[3]=x; bi[3]=ix; }
            }
        }
    }
    #pragma unroll
    for (int j = 0; j < 4; j++) cval[r][wv*4 + j] = bv[j];
    cidx4[r][wv] = (unsigned int)bi[0] | ((unsigned int)bi[1] << 8)
                 | ((unsigned int)bi[2] << 16) | ((unsigned int)bi[3] << 24);
    __syncthreads();

    // ---- Phase C: stage v into qb (granule ROTATION by row&7); wave0 merges + softmax ----
    #pragma unroll
    for (int i = 0; i < 4; i++) {
        int idx = tid + i * 256;
        int rr = idx >> 4, g = idx & 15;
        int gr = ((g + (rr & 7)) & 15) * 4;
        *(float4*)&qb[rr][gr] = v4[idx];
    }
    if (tid < 64) {
        float mv[4] = {-3.0e38f, -3.0e38f, -3.0e38f, -3.0e38f};
        int   mi[4] = {0, 0, 0, 0};
        #pragma unroll
        for (int w4 = 0; w4 < 4; w4++) {
            unsigned int ip = cidx4[tid][w4];
            #pragma unroll
            for (int j = 0; j < 4; j++) {
                float x = cval[tid][w4*4 + j];
                int ix = (int)((ip >> (8*j)) & 255u);
                if (x > mv[3]) {
                    if (x > mv[1]) {
                        if (x > mv[0]) { mv[3]=mv[2];mi[3]=mi[2]; mv[2]=mv[1];mi[2]=mi[1]; mv[1]=mv[0];mi[1]=mi[0]; mv[0]=x; mi[0]=ix; }
                        else           { mv[3]=mv[2];mi[3]=mi[2]; mv[2]=mv[1];mi[2]=mi[1]; mv[1]=x; mi[1]=ix; }
                    } else {
                        if (x > mv[2]) { mv[3]=mv[2];mi[3]=mi[2]; mv[2]=x; mi[2]=ix; }
                        else           { mv[3]=x; mi[3]=ix; }
                    }
                }
            }
        }
        // softmax over the 4 weights (order-invariant for the weighted sum)
        float m = mv[0];
        float e0 = __expf(mv[0]-m), e1 = __expf(mv[1]-m), e2 = __expf(mv[2]-m), e3 = __expf(mv[3]-m);
        float inv = 1.0f / (e0 + e1 + e2 + e3);
        wts[tid][0]=e0*inv; wts[tid][1]=e1*inv; wts[tid][2]=e2*inv; wts[tid][3]=e3*inv;
        dpack[tid] = (unsigned int)mi[0] | ((unsigned int)mi[1] << 8)
                   | ((unsigned int)mi[2] << 16) | ((unsigned int)mi[3] << 24);
    }
    __syncthreads();

    // ---- Phase D: V[r,j] = sum_i w_i * v[r, (j + delay_i) & 63] ----
    {
        const int rr = tid >> 2;           // row
        const int j0 = (tid & 3) * 16;     // this thread's 16 consecutive e's
        const int rot = (rr & 7) * 4;      // rotation applied at staging, folds into s
        const unsigned int dp = dpack[rr];
        float w[4]; int dl[4];
        #pragma unroll
        for (int i = 0; i < 4; i++) { w[i] = wts[rr][i]; dl[i] = (int)((dp >> (8*i)) & 63u); }
        float o[16];
        #pragma unroll
        for (int jj = 0; jj < 16; jj++) o[jj] = 0.f;
        #pragma unroll
        for (int i = 0; i < 4; i++) {
            int s = (j0 + dl[i] + rot) & 63;
            #pragma unroll
            for (int jj = 0; jj < 16; jj++) {
                o[jj] = fmaf(w[i], qb[rr][(s + jj) & 63], o[jj]);
            }
        }
        float* ov = outV + (rowbase + rr) * NE + j0;
        #pragma unroll
        for (int i = 0; i < 4; i++) {
            float4 t; t.x = o[i*4+0]; t.y = o[i*4+1]; t.z = o[i*4+2]; t.w = o[i*4+3];
            *(float4*)&ov[i*4] = t;
        }
    }
}

extern "C" void kernel_launch(void* const* d_in, const int* in_sizes, int n_in,
                              void* d_out, int out_size, void* d_ws, size_t ws_size,
                              hipStream_t stream) {
    const float* q = (const float*)d_in[0];
    const float* k = (const float*)d_in[1];
    const float* v = (const float*)d_in[2];
    float* outV = (float*)d_out;
    float* outC = outV + (size_t)NB * NH * NL * NE;   // V first, then transposed corr
    dim3 grid(NB * NH * (NL / 64));                   // 8192 blocks
    autocorr_kernel<<<grid, 256, 0, stream>>>(q, k, v, outV, outC);
}